// Round 17
// baseline (177.661 us; speedup 1.0000x reference)
//
#include <hip/hip_runtime.h>
#include <hip/hip_bf16.h>

#define D_IN   100
#define D_HID  256
#define D_OUT  40
#define BN_EPS 1e-5f
#define BSHIFT 8
#define P2_EPB 2048
#define P3_CAP 6144
#define NHIST  64
#define XC     13      // xb row = 13 uint4 chunks = 104 bf16 (cols 100..103 zero)

typedef short bf16x8 __attribute__((ext_vector_type(8)));
typedef float f32x4  __attribute__((ext_vector_type(4)));

__device__ inline float b2f(unsigned short u) {
    unsigned int x = ((unsigned int)u) << 16;
    return __builtin_bit_cast(float, x);
}
__device__ inline unsigned short f2b(float f) {
    unsigned int x = __builtin_bit_cast(unsigned int, f);
    unsigned int r = (x + 0x7fffu + ((x >> 16) & 1u)) >> 16;
    return (unsigned short)r;
}

// ================================================================ preprocess (fused):
// [0,nconv): x->xb[N][104] ; [nconv,+64): hist partials ; then W1, W2, zero-stats
__global__ __launch_bounds__(256) void preprocess(const float* __restrict__ X, short* __restrict__ Xb,
        int N, int nconv, const int* __restrict__ dst, int E, int* __restrict__ hpartial,
        const float* __restrict__ W1, const float* __restrict__ W2,
        short* __restrict__ Wt1b, short* __restrict__ Wt2b, float* __restrict__ stats) {
    __shared__ int h[256];
    int bid = blockIdx.x, tid = threadIdx.x;
    if (bid < nconv) {
        int t = bid * 256 + tid;
        int n = t / XC, c = t - n * XC;
        if (n >= N) return;
        unsigned short o[8];
        #pragma unroll
        for (int j = 0; j < 8; ++j) {
            int col = c * 8 + j;
            o[j] = (col < D_IN) ? f2b(X[(size_t)n * D_IN + col]) : (unsigned short)0;
        }
        *(uint4*)(Xb + (size_t)n * (XC * 8) + c * 8) = *(uint4*)o;
    } else if (bid < nconv + NHIST) {
        int hb = bid - nconv;
        h[tid] = 0;
        __syncthreads();
        for (int i = hb * 256 + tid; i < E; i += NHIST * 256)
            atomicAdd(&h[dst[i] >> BSHIFT], 1);
        __syncthreads();
        hpartial[hb * 256 + tid] = h[tid];
    } else {
        int pb = bid - nconv - NHIST;
        if (pb < 16) {
            int t = pb * 256 + tid;
            int n = t >> 4, ch = t & 15;
            unsigned short o[8];
            #pragma unroll
            for (int j = 0; j < 8; ++j) {
                int k = ch * 8 + j;
                o[j] = (k < D_IN) ? f2b(W1[(size_t)k * D_HID + n]) : (unsigned short)0;
            }
            *(uint4*)(Wt1b + (size_t)n * 128 + ch * 8) = *(uint4*)o;
        } else if (pb < 22) {
            int t = (pb - 16) * 256 + tid;
            int n = t >> 5, ch = t & 31;
            unsigned short o[8];
            #pragma unroll
            for (int j = 0; j < 8; ++j) {
                int k = ch * 8 + j;
                o[j] = (n < D_OUT) ? f2b(W2[(size_t)k * D_OUT + n]) : (unsigned short)0;
            }
            *(uint4*)(Wt2b + (size_t)n * 256 + ch * 8) = *(uint4*)o;
        } else {
            for (int i = tid; i < 640; i += 256) stats[i] = 0.f;
        }
    }
}

// ================================================================ bucket scan (reduce partials + scan)
__global__ __launch_bounds__(256) void bucket_scan(const int* __restrict__ hpartial,
        int* __restrict__ bbase, int* __restrict__ bcursor, int* __restrict__ rp,
        int NB, int N, int E) {
    __shared__ int A[256], B[256];
    int tid = threadIdx.x;
    int v = 0;
    #pragma unroll 8
    for (int b = 0; b < NHIST; ++b) v += hpartial[b * 256 + tid];
    A[tid] = v;
    __syncthreads();
    int* in = A; int* out = B;
    #pragma unroll
    for (int off = 1; off < 256; off <<= 1) {
        out[tid] = (tid >= off) ? (in[tid - off] + in[tid]) : in[tid];
        __syncthreads();
        int* t = in; in = out; out = t;
    }
    int excl = in[tid] - v;
    if (tid < NB) { bbase[tid] = excl; bcursor[tid] = excl; }
    if (tid == 0) { bbase[NB] = E; rp[N] = E; }
}

// ================================================================ partition edges -> packed pairs (src<<8 | dst&255), bucket-grouped
__global__ __launch_bounds__(256) void partition_edges(const int* __restrict__ src,
        const int* __restrict__ dst, int* __restrict__ bcursor,
        unsigned* __restrict__ pairs, int E) {
    __shared__ int hist[256];
    __shared__ int lbase[256];
    __shared__ int rbase[256];
    __shared__ int sA[256], sB[256];
    __shared__ uint2 st[P2_EPB];
    int tid = threadIdx.x;
    int base = blockIdx.x * P2_EPB;
    hist[tid] = 0;
    __syncthreads();
    int s[8], d[8], lo[8];
    #pragma unroll
    for (int p = 0; p < 8; ++p) {
        int i = base + p * 256 + tid;
        if (i < E) {
            s[p] = src[i]; d[p] = dst[i];
            lo[p] = atomicAdd(&hist[d[p] >> BSHIFT], 1);
        } else d[p] = -1;
    }
    __syncthreads();
    int v = hist[tid];
    sA[tid] = v;
    __syncthreads();
    int* in = sA; int* out = sB;
    #pragma unroll
    for (int off = 1; off < 256; off <<= 1) {
        out[tid] = (tid >= off) ? (in[tid - off] + in[tid]) : in[tid];
        __syncthreads();
        int* t = in; in = out; out = t;
    }
    lbase[tid] = in[tid] - v;
    if (v > 0) rbase[tid] = atomicAdd(&bcursor[tid], v);
    __syncthreads();
    #pragma unroll
    for (int p = 0; p < 8; ++p)
        if (d[p] >= 0)
            st[lbase[d[p] >> BSHIFT] + lo[p]] = make_uint2((unsigned)s[p], (unsigned)d[p]);
    __syncthreads();
    int cnt_total = min(P2_EPB, E - base);
    for (int i = tid; i < cnt_total; i += 256) {
        uint2 pr = st[i];
        int b = (int)(pr.y >> BSHIFT);
        pairs[rbase[b] + (i - lbase[b])] = (pr.x << 8) | (pr.y & 255u);
    }
}

// ================================================================ per-bucket fine CSR build (packed pairs)
__global__ __launch_bounds__(256) void build_csr(const unsigned* __restrict__ pairs,
        const int* __restrict__ bbase, int* __restrict__ rp, int* __restrict__ csr, int N) {
    __shared__ int hist[256];
    __shared__ int cur[256];
    __shared__ int sA[256], sB[256];
    __shared__ int ordered[P3_CAP];
    int tid = threadIdx.x;
    int b = blockIdx.x;
    int p0 = bbase[b], p1 = bbase[b + 1];
    int cnt = p1 - p0;
    hist[tid] = 0;
    __syncthreads();
    for (int i = tid; i < cnt; i += 256)
        atomicAdd(&hist[pairs[p0 + i] & 255u], 1);
    __syncthreads();
    int v = hist[tid];
    sA[tid] = v;
    __syncthreads();
    int* in = sA; int* out = sB;
    #pragma unroll
    for (int off = 1; off < 256; off <<= 1) {
        out[tid] = (tid >= off) ? (in[tid - off] + in[tid]) : in[tid];
        __syncthreads();
        int* t = in; in = out; out = t;
    }
    int excl = in[tid] - v;
    int dg = (b << BSHIFT) + tid;
    if (dg < N) rp[dg] = p0 + excl;
    cur[tid] = excl;
    __syncthreads();
    if (cnt <= P3_CAP) {
        for (int i = tid; i < cnt; i += 256) {
            unsigned pr = pairs[p0 + i];
            int off = atomicAdd(&cur[pr & 255u], 1);
            ordered[off] = (int)(pr >> 8);
        }
        __syncthreads();
        for (int i = tid; i < cnt; i += 256)
            csr[p0 + i] = ordered[i];
    } else {
        for (int i = tid; i < cnt; i += 256) {
            unsigned pr = pairs[p0 + i];
            int off = atomicAdd(&cur[pr & 255u], 1);
            csr[p0 + off] = (int)(pr >> 8);
        }
    }
}

// ================================================================ GEMM1 (MFMA, BM=32, staged Wl) with FUSED gather
// gather: 2 rows per thread (r, r+16), interleaved edge loops -> 8 loads in flight
__global__ __launch_bounds__(256) void gemm1_fused(const short* __restrict__ Xb,
                                                   const int* __restrict__ rp, const int* __restrict__ csr,
                                                   const short* __restrict__ Wtb,
                                                   const float* __restrict__ bias,
                                                   short* __restrict__ Hb, int N) {
    __shared__ short Al[32 * 136];
    __shared__ short Wl[64 * 136];
    int tid = threadIdx.x;
    int r0 = blockIdx.x * 32;
    int w = tid >> 6, l = tid & 63;
    int r16 = l & 15, g4 = l >> 4;
    int chunk = tid & 15, rbase = tid >> 4;
    const uint4* Xc = (const uint4*)Xb;

    // ---- gather phase: rows (tid>>4) and (tid>>4)+16, chunk tid&15
    {
        int ch = tid & 15;
        int row0 = tid >> 4;
        int row1 = row0 + 16;
        int m0 = r0 + row0, m1 = r0 + row1;
        if (ch >= XC) {
            *(uint4*)(Al + row0 * 136 + ch * 8) = make_uint4(0, 0, 0, 0);
            *(uint4*)(Al + row1 * 136 + ch * 8) = make_uint4(0, 0, 0, 0);
        } else {
            float a0[8], a1[8];
            #pragma unroll
            for (int j = 0; j < 8; ++j) { a0[j] = 0.f; a1[j] = 0.f; }
            int ea = 0, eA = 0, eb = 0, eB = 0;
            if (m0 < N) {
                uint4 v = Xc[(size_t)m0 * XC + ch];
                #pragma unroll
                for (int j = 0; j < 8; ++j) a0[j] = b2f(((const unsigned short*)&v)[j]);
                ea = rp[m0]; eA = rp[m0 + 1];
            }
            if (m1 < N) {
                uint4 v = Xc[(size_t)m1 * XC + ch];
                #pragma unroll
                for (int j = 0; j < 8; ++j) a1[j] = b2f(((const unsigned short*)&v)[j]);
                eb = rp[m1]; eB = rp[m1 + 1];
            }
            // common interleaved phase: 4 loads per row, 8 in flight
            while (ea + 4 <= eA && eb + 4 <= eB) {
                int s0 = csr[ea], s1 = csr[ea + 1], s2 = csr[ea + 2], s3 = csr[ea + 3];
                int t0 = csr[eb], t1 = csr[eb + 1], t2 = csr[eb + 2], t3 = csr[eb + 3];
                uint4 u0 = Xc[(size_t)s0 * XC + ch];
                uint4 u1 = Xc[(size_t)s1 * XC + ch];
                uint4 u2 = Xc[(size_t)s2 * XC + ch];
                uint4 u3 = Xc[(size_t)s3 * XC + ch];
                uint4 w0 = Xc[(size_t)t0 * XC + ch];
                uint4 w1 = Xc[(size_t)t1 * XC + ch];
                uint4 w2 = Xc[(size_t)t2 * XC + ch];
                uint4 w3 = Xc[(size_t)t3 * XC + ch];
                #pragma unroll
                for (int j = 0; j < 8; ++j) {
                    a0[j] += (b2f(((const unsigned short*)&u0)[j]) + b2f(((const unsigned short*)&u1)[j]))
                           + (b2f(((const unsigned short*)&u2)[j]) + b2f(((const unsigned short*)&u3)[j]));
                    a1[j] += (b2f(((const unsigned short*)&w0)[j]) + b2f(((const unsigned short*)&w1)[j]))
                           + (b2f(((const unsigned short*)&w2)[j]) + b2f(((const unsigned short*)&w3)[j]));
                }
                ea += 4; eb += 4;
            }
            // drain row0
            for (; ea + 4 <= eA; ea += 4) {
                int s0 = csr[ea], s1 = csr[ea + 1], s2 = csr[ea + 2], s3 = csr[ea + 3];
                uint4 u0 = Xc[(size_t)s0 * XC + ch];
                uint4 u1 = Xc[(size_t)s1 * XC + ch];
                uint4 u2 = Xc[(size_t)s2 * XC + ch];
                uint4 u3 = Xc[(size_t)s3 * XC + ch];
                #pragma unroll
                for (int j = 0; j < 8; ++j)
                    a0[j] += (b2f(((const unsigned short*)&u0)[j]) + b2f(((const unsigned short*)&u1)[j]))
                           + (b2f(((const unsigned short*)&u2)[j]) + b2f(((const unsigned short*)&u3)[j]));
            }
            for (; ea < eA; ++ea) {
                int s = csr[ea];
                uint4 u = Xc[(size_t)s * XC + ch];
                #pragma unroll
                for (int j = 0; j < 8; ++j) a0[j] += b2f(((const unsigned short*)&u)[j]);
            }
            // drain row1
            for (; eb + 4 <= eB; eb += 4) {
                int t0 = csr[eb], t1 = csr[eb + 1], t2 = csr[eb + 2], t3 = csr[eb + 3];
                uint4 w0 = Xc[(size_t)t0 * XC + ch];
                uint4 w1 = Xc[(size_t)t1 * XC + ch];
                uint4 w2 = Xc[(size_t)t2 * XC + ch];
                uint4 w3 = Xc[(size_t)t3 * XC + ch];
                #pragma unroll
                for (int j = 0; j < 8; ++j)
                    a1[j] += (b2f(((const unsigned short*)&w0)[j]) + b2f(((const unsigned short*)&w1)[j]))
                           + (b2f(((const unsigned short*)&w2)[j]) + b2f(((const unsigned short*)&w3)[j]));
            }
            for (; eb < eB; ++eb) {
                int t = csr[eb];
                uint4 u = Xc[(size_t)t * XC + ch];
                #pragma unroll
                for (int j = 0; j < 8; ++j) a1[j] += b2f(((const unsigned short*)&u)[j]);
            }
            unsigned short o0[8], o1[8];
            #pragma unroll
            for (int j = 0; j < 8; ++j) { o0[j] = f2b(a0[j]); o1[j] = f2b(a1[j]); }
            *(uint4*)(Al + row0 * 136 + ch * 8) = *(uint4*)o0;
            *(uint4*)(Al + row1 * 136 + ch * 8) = *(uint4*)o1;
        }
    }

    // ---- MFMA phase: wave w -> row strip (w&1)*16, n-half (w>>1)
    int strip = (w & 1) * 16;
    int nh = w >> 1;
    int m = r0 + strip + r16;
    bf16x8 af[4];
    #pragma unroll
    for (int ct = 0; ct < 4; ++ct) {
        __syncthreads();                 // ct=0: gather done; else: prev compute done
        #pragma unroll
        for (int p = 0; p < 4; ++p) {    // stage Wt col-tile [64][128]
            int row = p * 16 + rbase;
            *(uint4*)(Wl + row * 136 + chunk * 8) =
                *(const uint4*)(Wtb + (size_t)(ct * 64 + row) * 128 + chunk * 8);
        }
        __syncthreads();
        if (ct == 0) {
            #pragma unroll
            for (int k = 0; k < 4; ++k)
                af[k] = *(bf16x8*)(Al + (strip + r16) * 136 + k * 32 + g4 * 8);
        }
        #pragma unroll
        for (int nn = 0; nn < 2; ++nn) {
            int n = nh * 2 + nn;
            f32x4 acc = {0.f, 0.f, 0.f, 0.f};
            #pragma unroll
            for (int k = 0; k < 4; ++k) {
                bf16x8 wf = *(bf16x8*)(Wl + (n * 16 + r16) * 136 + k * 32 + g4 * 8);
                acc = __builtin_amdgcn_mfma_f32_16x16x32_bf16(wf, af[k], acc, 0, 0, 0);
            }
            int nc = ct * 64 + n * 16 + g4 * 4;
            float4 b4 = *(const float4*)(bias + nc);
            if (m < N) {
                ushort4 o;
                o.x = f2b(acc[0] + b4.x);
                o.y = f2b(acc[1] + b4.y);
                o.z = f2b(acc[2] + b4.z);
                o.w = f2b(acc[3] + b4.w);
                *(ushort4*)(Hb + (size_t)m * 256 + nc) = o;
            }
        }
    }
}

// ================================================================ column stats bf16 [N][256] — vectorized uint4 loads
__global__ __launch_bounds__(256) void stats_hid_b(const short* __restrict__ H, int N,
                                                   float* __restrict__ sum, float* __restrict__ sumsq) {
    __shared__ float red[8 * 256];
    int tid = threadIdx.x;
    int c8 = tid & 31;
    int rg = tid >> 5;
    float s[8], q[8];
    #pragma unroll
    for (int j = 0; j < 8; ++j) { s[j] = 0.f; q[j] = 0.f; }
    for (int r = blockIdx.x * 8 + rg; r < N; r += gridDim.x * 8) {
        uint4 v = *(const uint4*)(H + (size_t)r * 256 + c8 * 8);
        #pragma unroll
        for (int j = 0; j < 8; ++j) {
            float f = b2f(((const unsigned short*)&v)[j]);
            s[j] += f; q[j] += f * f;
        }
    }
    #pragma unroll
    for (int j = 0; j < 8; ++j) red[rg * 256 + c8 * 8 + j] = s[j];
    __syncthreads();
    {
        float t = 0.f;
        #pragma unroll
        for (int g = 0; g < 8; ++g) t += red[g * 256 + tid];
        atomicAdd(&sum[tid], t);
    }
    __syncthreads();
    #pragma unroll
    for (int j = 0; j < 8; ++j) red[rg * 256 + c8 * 8 + j] = q[j];
    __syncthreads();
    {
        float t = 0.f;
        #pragma unroll
        for (int g = 0; g < 8; ++g) t += red[g * 256 + tid];
        atomicAdd(&sumsq[tid], t);
    }
}

// ================================================================ GEMM2 (MFMA, BM=64): z = relu(bn1(hpreb)) @ W2 -> bf16 [N][40]
__global__ __launch_bounds__(256) void gemm2_mfma(const short* __restrict__ Hb,
                                                  const short* __restrict__ Wtb,
                                                  const float* __restrict__ colsum, const float* __restrict__ colsumsq,
                                                  const float* __restrict__ gamma, const float* __restrict__ beta,
                                                  float invN, short* __restrict__ Zb, int N) {
    __shared__ short Al[64 * 136];
    __shared__ short Wl[48 * 136];
    __shared__ float scl[D_HID], shl[D_HID];
    int tid = threadIdx.x;
    {
        float m = colsum[tid] * invN;
        float var = colsumsq[tid] * invN - m * m;
        float rstd = rsqrtf(var + BN_EPS);
        float sc = rstd * gamma[tid];
        scl[tid] = sc;
        shl[tid] = beta[tid] - m * sc;
    }
    int r0 = blockIdx.x * 64;
    int w = tid >> 6, l = tid & 63;
    int r16 = l & 15, g4 = l >> 4;
    int chunk = tid & 15, rbase = tid >> 4;
    f32x4 acc[3];
    #pragma unroll
    for (int n = 0; n < 3; ++n)
        acc[n] = (f32x4){0.f, 0.f, 0.f, 0.f};

    #pragma unroll
    for (int h = 0; h < 2; ++h) {
        __syncthreads();                 // h=0: scl ready; h=1: prev compute done
        int kb = h * 128;
        #pragma unroll
        for (int p = 0; p < 4; ++p) {    // stage A half [64][16ch] with BN+ReLU
            int row = p * 16 + rbase;
            int m = r0 + row;
            uint4 v = make_uint4(0, 0, 0, 0);
            if (m < N) v = *(const uint4*)(Hb + (size_t)m * 256 + kb + chunk * 8);
            unsigned short* us = (unsigned short*)&v;
            #pragma unroll
            for (int j = 0; j < 8; ++j) {
                int k = kb + chunk * 8 + j;
                float f = b2f(us[j]);
                f = fmaxf(f * scl[k] + shl[k], 0.f);
                us[j] = f2b(f);
            }
            *(uint4*)(Al + row * 136 + chunk * 8) = v;
        }
        #pragma unroll
        for (int p = 0; p < 3; ++p) {    // stage Wt2 half [48][16ch]
            int row = p * 16 + rbase;
            *(uint4*)(Wl + row * 136 + chunk * 8) =
                *(const uint4*)(Wtb + (size_t)row * 256 + kb + chunk * 8);
        }
        __syncthreads();
        bf16x8 wf[3][4];
        #pragma unroll
        for (int n = 0; n < 3; ++n)
            #pragma unroll
            for (int k = 0; k < 4; ++k)
                wf[n][k] = *(bf16x8*)(Wl + (n * 16 + r16) * 136 + k * 32 + g4 * 8);
        #pragma unroll
        for (int k = 0; k < 4; ++k) {
            bf16x8 af = *(bf16x8*)(Al + (w * 16 + r16) * 136 + k * 32 + g4 * 8);
            #pragma unroll
            for (int n = 0; n < 3; ++n)
                acc[n] = __builtin_amdgcn_mfma_f32_16x16x32_bf16(wf[n][k], af, acc[n], 0, 0, 0);
        }
    }
    int m = r0 + w * 16 + r16;
    if (m < N) {
        #pragma unroll
        for (int n = 0; n < 3; ++n) {
            int nc = n * 16 + g4 * 4;
            if (nc < D_OUT) {
                ushort4 o;
                o.x = f2b(acc[n][0]);
                o.y = f2b(acc[n][1]);
                o.z = f2b(acc[n][2]);
                o.w = f2b(acc[n][3]);
                *(ushort4*)(Zb + (size_t)m * D_OUT + nc) = o;
            }
        }
    }
}

// ================================================================ gather2 + fused column stats (bf16 z, bf16 h2 out, 8/4/1 ILP)
__global__ __launch_bounds__(256) void gather2_stats(const short* __restrict__ Zb,
        const int* __restrict__ rp, const int* __restrict__ csr,
        const float* __restrict__ bias, short* __restrict__ H2b,
        float* __restrict__ gsum, float* __restrict__ gsumsq, int N) {
    __shared__ float ls[D_OUT], lq[D_OUT];
    int tid = threadIdx.x;
    if (tid < D_OUT) { ls[tid] = 0.f; lq[tid] = 0.f; }
    __syncthreads();
    int t = blockIdx.x * 256 + tid;
    int n = t / 5, c = t - n * 5;
    if (n < N) {
        const uint4* Zc = (const uint4*)Zb + c;
        float acc[8];
        {
            uint4 v = Zc[(size_t)n * 5];
            #pragma unroll
            for (int j = 0; j < 8; ++j) acc[j] = b2f(((const unsigned short*)&v)[j]);
        }
        int e0 = rp[n], e1 = rp[n + 1];
        int e = e0;
        for (; e + 8 <= e1; e += 8) {
            int si[8];
            #pragma unroll
            for (int q = 0; q < 8; ++q) si[q] = csr[e + q];
            uint4 u[8];
            #pragma unroll
            for (int q = 0; q < 8; ++q) u[q] = Zc[(size_t)si[q] * 5];
            #pragma unroll
            for (int j = 0; j < 8; ++j) {
                float a0 = 0.f, a1 = 0.f;
                #pragma unroll
                for (int q = 0; q < 8; q += 2) {
                    a0 += b2f(((const unsigned short*)&u[q])[j]);
                    a1 += b2f(((const unsigned short*)&u[q + 1])[j]);
                }
                acc[j] += a0 + a1;
            }
        }
        for (; e + 4 <= e1; e += 4) {
            int s0 = csr[e], s1 = csr[e + 1], s2 = csr[e + 2], s3 = csr[e + 3];
            uint4 u0 = Zc[(size_t)s0 * 5];
            uint4 u1 = Zc[(size_t)s1 * 5];
            uint4 u2 = Zc[(size_t)s2 * 5];
            uint4 u3 = Zc[(size_t)s3 * 5];
            #pragma unroll
            for (int j = 0; j < 8; ++j)
                acc[j] += (b2f(((const unsigned short*)&u0)[j]) + b2f(((const unsigned short*)&u1)[j]))
                        + (b2f(((const unsigned short*)&u2)[j]) + b2f(((const unsigned short*)&u3)[j]));
        }
        for (; e < e1; ++e) {
            int s = csr[e];
            uint4 u = Zc[(size_t)s * 5];
            #pragma unroll
            for (int j = 0; j < 8; ++j) acc[j] += b2f(((const unsigned short*)&u)[j]);
        }
        int cc = c * 8;
        unsigned short o[8];
        #pragma unroll
        for (int j = 0; j < 8; ++j) {
            acc[j] += bias[cc + j];
            atomicAdd(&ls[cc + j], acc[j]);
            atomicAdd(&lq[cc + j], acc[j] * acc[j]);
            o[j] = f2b(acc[j]);
        }
        *(uint4*)(H2b + (size_t)n * D_OUT + cc) = *(uint4*)o;
    }
    __syncthreads();
    if (tid < D_OUT) {
        atomicAdd(&gsum[tid], ls[tid]);
        atomicAdd(&gsumsq[tid], lq[tid]);
    }
}

// ================================================================ BN2 + log_softmax (bf16 input)
__global__ __launch_bounds__(256) void bn_logsoftmax(const short* __restrict__ Hb,
                                                     const float* __restrict__ colsum, const float* __restrict__ colsumsq,
                                                     const float* __restrict__ gamma, const float* __restrict__ beta,
                                                     float invN, float* __restrict__ out, int N) {
    __shared__ float buf[256 * 41];
    __shared__ float scl[D_OUT], shl[D_OUT];
    int tid = threadIdx.x;
    if (tid < D_OUT) {
        float m = colsum[tid] * invN;
        float var = colsumsq[tid] * invN - m * m;
        float rstd = rsqrtf(var + BN_EPS);
        float sc = rstd * gamma[tid];
        scl[tid] = sc;
        shl[tid] = beta[tid] - m * sc;
    }
    const unsigned short* Hu = (const unsigned short*)Hb;
    int r0 = blockIdx.x * 256;
    int nrow = min(256, N - r0);
    int total = nrow * D_OUT;
    __syncthreads();
    for (int i = tid; i < total; i += 256)
        buf[i + i / D_OUT] = b2f(Hu[(size_t)r0 * D_OUT + i]);
    __syncthreads();
    if (tid < nrow) {
        int base = tid * 41;
        float m = -1e30f;
        #pragma unroll
        for (int j = 0; j < D_OUT; ++j) {
            float v = buf[base + j] * scl[j] + shl[j];
            buf[base + j] = v;
            m = fmaxf(m, v);
        }
        float s = 0.f;
        #pragma unroll
        for (int j = 0; j < D_OUT; ++j)
            s += expf(buf[base + j] - m);
        float lse = m + logf(s);
        #pragma unroll
        for (int j = 0; j < D_OUT; ++j)
            buf[base + j] -= lse;
    }
    __syncthreads();
    for (int i = tid; i < total; i += 256)
        out[(size_t)r0 * D_OUT + i] = buf[i + i / D_OUT];
}

// =================================================================
extern "C" void kernel_launch(void* const* d_in, const int* in_sizes, int n_in,
                              void* d_out, int out_size, void* d_ws, size_t ws_size,
                              hipStream_t stream) {
    const float* x      = (const float*)d_in[0];
    const int*   ei     = (const int*)d_in[1];
    const float* W1     = (const float*)d_in[2];
    const float* b1     = (const float*)d_in[3];
    const float* W2     = (const float*)d_in[4];
    const float* b2     = (const float*)d_in[5];
    const float* gamma1 = (const float*)d_in[6];
    const float* beta1  = (const float*)d_in[7];
    const float* gamma2 = (const float*)d_in[8];
    const float* beta2  = (const float*)d_in[9];
    float* out = (float*)d_out;

    const int N = in_sizes[0] / D_IN;      // 50000
    const int E = in_sizes[1] / 2;         // 800000
    const int* src = ei;
    const int* dst = ei + E;
    const int nbk = (N + 255) >> BSHIFT;   // 196
    const int nconv = (N * XC + 255) / 256;

    // ---------------- workspace layout ----------------
    short* xb    = (short*)d_ws;                       // N*104 bf16
    short* hpreb = xb + (size_t)N * (XC * 8);          // N*256 bf16
    short* Wt1b  = hpreb + (size_t)N * 256;            // 256*128
    short* Wt2b  = Wt1b + 256 * 128;                   // 48*256
    short* zb    = Wt2b + 48 * 256;                    // N*40 bf16
    short* h2b   = zb + (size_t)N * D_OUT;             // N*40 bf16
    float* stats = (float*)(h2b + (size_t)N * D_OUT + 64);  // 640 f32
    float* colsum1   = stats + 0;     // 256
    float* colsumsq1 = stats + 256;   // 256
    float* colsum2   = stats + 512;   // 40 (pad 64)
    float* colsumsq2 = stats + 576;   // 40 (pad 64)
    int* rp       = (int*)(stats + 640);  // N+1 (pad N+4)
    int* hpartial = rp + N + 4;           // 64*256
    int* bbase    = hpartial + NHIST*256; // 260
    int* bcursor  = bbase + 260;          // 256
    int* csr      = bcursor + 256;        // E
    unsigned* pairs = (unsigned*)(csr + E);  // E (packed)

    // ---------------- fused prep + CSR build ----------------
    preprocess<<<nconv + NHIST + 23, 256, 0, stream>>>(x, xb, N, nconv, dst, E, hpartial,
                                                       W1, W2, Wt1b, Wt2b, stats);
    bucket_scan<<<1, 256, 0, stream>>>(hpartial, bbase, bcursor, rp, nbk, N, E);
    partition_edges<<<(E + P2_EPB - 1) / P2_EPB, 256, 0, stream>>>(src, dst, bcursor, pairs, E);
    build_csr<<<nbk, 256, 0, stream>>>(pairs, bbase, rp, csr, N);

    // ---------------- layer 1 (gather fused into GEMM1, BM=32, interleaved 2-row gather) ----------------
    gemm1_fused<<<(N + 31) / 32, 256, 0, stream>>>(xb, rp, csr, Wt1b, b1, hpreb, N);
    stats_hid_b<<<512, 256, 0, stream>>>(hpreb, N, colsum1, colsumsq1);

    // ---------------- layer 2 (BM=64) ----------------
    gemm2_mfma<<<(N + 63) / 64, 256, 0, stream>>>(hpreb, Wt2b, colsum1, colsumsq1,
                                                  gamma1, beta1, 1.0f / N, zb, N);
    gather2_stats<<<(N * 5 + 255) / 256, 256, 0, stream>>>(zb, rp, csr, b2, h2b,
                                                           colsum2, colsumsq2, N);

    // ---------------- BN2 + log_softmax ----------------
    bn_logsoftmax<<<(N + 255) / 256, 256, 0, stream>>>(h2b, colsum2, colsumsq2,
                                                       gamma2, beta2, 1.0f / N, out, N);
}

// Round 18
// 173.245 us; speedup vs baseline: 1.0255x; 1.0255x over previous
//
#include <hip/hip_runtime.h>
#include <hip/hip_bf16.h>

#define D_IN   100
#define D_HID  256
#define D_OUT  40
#define BN_EPS 1e-5f
#define BSHIFT 8
#define P2_EPB 2048
#define P3_CAP 6144
#define NHIST  64
#define XC     13      // xb row = 13 uint4 chunks = 104 bf16 (cols 100..103 zero)

typedef short bf16x8 __attribute__((ext_vector_type(8)));
typedef float f32x4  __attribute__((ext_vector_type(4)));

__device__ inline float b2f(unsigned short u) {
    unsigned int x = ((unsigned int)u) << 16;
    return __builtin_bit_cast(float, x);
}
__device__ inline unsigned short f2b(float f) {
    unsigned int x = __builtin_bit_cast(unsigned int, f);
    unsigned int r = (x + 0x7fffu + ((x >> 16) & 1u)) >> 16;
    return (unsigned short)r;
}

// ================================================================ preprocess (fused):
// [0,nconv): x->xb[N][104] ; [nconv,+64): hist partials ; then W1, W2, zero-stats
__global__ __launch_bounds__(256) void preprocess(const float* __restrict__ X, short* __restrict__ Xb,
        int N, int nconv, const int* __restrict__ dst, int E, int* __restrict__ hpartial,
        const float* __restrict__ W1, const float* __restrict__ W2,
        short* __restrict__ Wt1b, short* __restrict__ Wt2b, float* __restrict__ stats) {
    __shared__ int h[256];
    int bid = blockIdx.x, tid = threadIdx.x;
    if (bid < nconv) {
        int t = bid * 256 + tid;
        int n = t / XC, c = t - n * XC;
        if (n >= N) return;
        unsigned short o[8];
        #pragma unroll
        for (int j = 0; j < 8; ++j) {
            int col = c * 8 + j;
            o[j] = (col < D_IN) ? f2b(X[(size_t)n * D_IN + col]) : (unsigned short)0;
        }
        *(uint4*)(Xb + (size_t)n * (XC * 8) + c * 8) = *(uint4*)o;
    } else if (bid < nconv + NHIST) {
        int hb = bid - nconv;
        h[tid] = 0;
        __syncthreads();
        for (int i = hb * 256 + tid; i < E; i += NHIST * 256)
            atomicAdd(&h[dst[i] >> BSHIFT], 1);
        __syncthreads();
        hpartial[hb * 256 + tid] = h[tid];
    } else {
        int pb = bid - nconv - NHIST;
        if (pb < 16) {
            int t = pb * 256 + tid;
            int n = t >> 4, ch = t & 15;
            unsigned short o[8];
            #pragma unroll
            for (int j = 0; j < 8; ++j) {
                int k = ch * 8 + j;
                o[j] = (k < D_IN) ? f2b(W1[(size_t)k * D_HID + n]) : (unsigned short)0;
            }
            *(uint4*)(Wt1b + (size_t)n * 128 + ch * 8) = *(uint4*)o;
        } else if (pb < 22) {
            int t = (pb - 16) * 256 + tid;
            int n = t >> 5, ch = t & 31;
            unsigned short o[8];
            #pragma unroll
            for (int j = 0; j < 8; ++j) {
                int k = ch * 8 + j;
                o[j] = (n < D_OUT) ? f2b(W2[(size_t)k * D_OUT + n]) : (unsigned short)0;
            }
            *(uint4*)(Wt2b + (size_t)n * 256 + ch * 8) = *(uint4*)o;
        } else {
            for (int i = tid; i < 640; i += 256) stats[i] = 0.f;
        }
    }
}

// ================================================================ bucket scan (reduce partials + scan)
__global__ __launch_bounds__(256) void bucket_scan(const int* __restrict__ hpartial,
        int* __restrict__ bbase, int* __restrict__ bcursor, int* __restrict__ rp,
        int NB, int N, int E) {
    __shared__ int A[256], B[256];
    int tid = threadIdx.x;
    int v = 0;
    #pragma unroll 8
    for (int b = 0; b < NHIST; ++b) v += hpartial[b * 256 + tid];
    A[tid] = v;
    __syncthreads();
    int* in = A; int* out = B;
    #pragma unroll
    for (int off = 1; off < 256; off <<= 1) {
        out[tid] = (tid >= off) ? (in[tid - off] + in[tid]) : in[tid];
        __syncthreads();
        int* t = in; in = out; out = t;
    }
    int excl = in[tid] - v;
    if (tid < NB) { bbase[tid] = excl; bcursor[tid] = excl; }
    if (tid == 0) { bbase[NB] = E; rp[N] = E; }
}

// ================================================================ partition edges -> packed pairs (src<<8 | dst&255), bucket-grouped
__global__ __launch_bounds__(256) void partition_edges(const int* __restrict__ src,
        const int* __restrict__ dst, int* __restrict__ bcursor,
        unsigned* __restrict__ pairs, int E) {
    __shared__ int hist[256];
    __shared__ int lbase[256];
    __shared__ int rbase[256];
    __shared__ int sA[256], sB[256];
    __shared__ uint2 st[P2_EPB];
    int tid = threadIdx.x;
    int base = blockIdx.x * P2_EPB;
    hist[tid] = 0;
    __syncthreads();
    int s[8], d[8], lo[8];
    #pragma unroll
    for (int p = 0; p < 8; ++p) {
        int i = base + p * 256 + tid;
        if (i < E) {
            s[p] = src[i]; d[p] = dst[i];
            lo[p] = atomicAdd(&hist[d[p] >> BSHIFT], 1);
        } else d[p] = -1;
    }
    __syncthreads();
    int v = hist[tid];
    sA[tid] = v;
    __syncthreads();
    int* in = sA; int* out = sB;
    #pragma unroll
    for (int off = 1; off < 256; off <<= 1) {
        out[tid] = (tid >= off) ? (in[tid - off] + in[tid]) : in[tid];
        __syncthreads();
        int* t = in; in = out; out = t;
    }
    lbase[tid] = in[tid] - v;
    if (v > 0) rbase[tid] = atomicAdd(&bcursor[tid], v);
    __syncthreads();
    #pragma unroll
    for (int p = 0; p < 8; ++p)
        if (d[p] >= 0)
            st[lbase[d[p] >> BSHIFT] + lo[p]] = make_uint2((unsigned)s[p], (unsigned)d[p]);
    __syncthreads();
    int cnt_total = min(P2_EPB, E - base);
    for (int i = tid; i < cnt_total; i += 256) {
        uint2 pr = st[i];
        int b = (int)(pr.y >> BSHIFT);
        pairs[rbase[b] + (i - lbase[b])] = (pr.x << 8) | (pr.y & 255u);
    }
}

// ================================================================ per-bucket fine CSR build (packed pairs)
__global__ __launch_bounds__(256) void build_csr(const unsigned* __restrict__ pairs,
        const int* __restrict__ bbase, int* __restrict__ rp, int* __restrict__ csr, int N) {
    __shared__ int hist[256];
    __shared__ int cur[256];
    __shared__ int sA[256], sB[256];
    __shared__ int ordered[P3_CAP];
    int tid = threadIdx.x;
    int b = blockIdx.x;
    int p0 = bbase[b], p1 = bbase[b + 1];
    int cnt = p1 - p0;
    hist[tid] = 0;
    __syncthreads();
    for (int i = tid; i < cnt; i += 256)
        atomicAdd(&hist[pairs[p0 + i] & 255u], 1);
    __syncthreads();
    int v = hist[tid];
    sA[tid] = v;
    __syncthreads();
    int* in = sA; int* out = sB;
    #pragma unroll
    for (int off = 1; off < 256; off <<= 1) {
        out[tid] = (tid >= off) ? (in[tid - off] + in[tid]) : in[tid];
        __syncthreads();
        int* t = in; in = out; out = t;
    }
    int excl = in[tid] - v;
    int dg = (b << BSHIFT) + tid;
    if (dg < N) rp[dg] = p0 + excl;
    cur[tid] = excl;
    __syncthreads();
    if (cnt <= P3_CAP) {
        for (int i = tid; i < cnt; i += 256) {
            unsigned pr = pairs[p0 + i];
            int off = atomicAdd(&cur[pr & 255u], 1);
            ordered[off] = (int)(pr >> 8);
        }
        __syncthreads();
        for (int i = tid; i < cnt; i += 256)
            csr[p0 + i] = ordered[i];
    } else {
        for (int i = tid; i < cnt; i += 256) {
            unsigned pr = pairs[p0 + i];
            int off = atomicAdd(&cur[pr & 255u], 1);
            csr[p0 + off] = (int)(pr >> 8);
        }
    }
}

// ================================================================ GEMM1 (MFMA, BM=64, staged Wl) with FUSED gather
__global__ __launch_bounds__(256) void gemm1_fused(const short* __restrict__ Xb,
                                                   const int* __restrict__ rp, const int* __restrict__ csr,
                                                   const short* __restrict__ Wtb,
                                                   const float* __restrict__ bias,
                                                   short* __restrict__ Hb, int N) {
    __shared__ short Al[64 * 136];
    __shared__ short Wl[64 * 136];
    int tid = threadIdx.x;
    int r0 = blockIdx.x * 64;
    int w = tid >> 6, l = tid & 63;
    int r16 = l & 15, g4 = l >> 4;
    int chunk = tid & 15, rbase = tid >> 4;
    const uint4* Xc = (const uint4*)Xb;

    // ---- gather phase: build A-tile [64 rows][16 chunks] in LDS (chunks 13..15 zero)
    #pragma unroll
    for (int p = 0; p < 4; ++p) {
        int idx = p * 256 + tid;
        int row = idx >> 4, ch = idx & 15;
        int m = r0 + row;
        if (ch >= XC || m >= N) {
            *(uint4*)(Al + row * 136 + ch * 8) = make_uint4(0, 0, 0, 0);
            continue;
        }
        float acc[8];
        {
            uint4 v = Xc[(size_t)m * XC + ch];
            #pragma unroll
            for (int j = 0; j < 8; ++j) acc[j] = b2f(((const unsigned short*)&v)[j]);
        }
        int e0 = rp[m], e1 = rp[m + 1];
        int e = e0;
        for (; e + 8 <= e1; e += 8) {
            int si[8];
            #pragma unroll
            for (int q = 0; q < 8; ++q) si[q] = csr[e + q];
            uint4 u[8];
            #pragma unroll
            for (int q = 0; q < 8; ++q) u[q] = Xc[(size_t)si[q] * XC + ch];
            #pragma unroll
            for (int j = 0; j < 8; ++j) {
                float a0 = 0.f, a1 = 0.f;
                #pragma unroll
                for (int q = 0; q < 8; q += 2) {
                    a0 += b2f(((const unsigned short*)&u[q])[j]);
                    a1 += b2f(((const unsigned short*)&u[q + 1])[j]);
                }
                acc[j] += a0 + a1;
            }
        }
        for (; e + 4 <= e1; e += 4) {
            int s0 = csr[e], s1 = csr[e + 1], s2 = csr[e + 2], s3 = csr[e + 3];
            uint4 u0 = Xc[(size_t)s0 * XC + ch];
            uint4 u1 = Xc[(size_t)s1 * XC + ch];
            uint4 u2 = Xc[(size_t)s2 * XC + ch];
            uint4 u3 = Xc[(size_t)s3 * XC + ch];
            #pragma unroll
            for (int j = 0; j < 8; ++j)
                acc[j] += (b2f(((const unsigned short*)&u0)[j]) + b2f(((const unsigned short*)&u1)[j]))
                        + (b2f(((const unsigned short*)&u2)[j]) + b2f(((const unsigned short*)&u3)[j]));
        }
        for (; e < e1; ++e) {
            int s = csr[e];
            uint4 u = Xc[(size_t)s * XC + ch];
            #pragma unroll
            for (int j = 0; j < 8; ++j) acc[j] += b2f(((const unsigned short*)&u)[j]);
        }
        unsigned short o[8];
        #pragma unroll
        for (int j = 0; j < 8; ++j) o[j] = f2b(acc[j]);
        *(uint4*)(Al + row * 136 + ch * 8) = *(uint4*)o;
    }

    // ---- MFMA phase: each wave owns 16-row strip w*16
    bf16x8 af[4];
    int m = r0 + w * 16 + r16;
    #pragma unroll
    for (int ct = 0; ct < 4; ++ct) {
        __syncthreads();                 // ct=0: gather done; else: prev compute done
        #pragma unroll
        for (int p = 0; p < 4; ++p) {    // stage Wt col-tile [64][128]
            int row = p * 16 + rbase;
            *(uint4*)(Wl + row * 136 + chunk * 8) =
                *(const uint4*)(Wtb + (size_t)(ct * 64 + row) * 128 + chunk * 8);
        }
        __syncthreads();
        if (ct == 0) {
            #pragma unroll
            for (int k = 0; k < 4; ++k)
                af[k] = *(bf16x8*)(Al + (w * 16 + r16) * 136 + k * 32 + g4 * 8);
        }
        bf16x8 wf[4][4];
        #pragma unroll
        for (int n = 0; n < 4; ++n)
            #pragma unroll
            for (int k = 0; k < 4; ++k)
                wf[n][k] = *(bf16x8*)(Wl + (n * 16 + r16) * 136 + k * 32 + g4 * 8);
        #pragma unroll
        for (int n = 0; n < 4; ++n) {
            f32x4 acc = {0.f, 0.f, 0.f, 0.f};
            #pragma unroll
            for (int k = 0; k < 4; ++k)
                acc = __builtin_amdgcn_mfma_f32_16x16x32_bf16(wf[n][k], af[k], acc, 0, 0, 0);
            int nc = ct * 64 + n * 16 + g4 * 4;
            float4 b4 = *(const float4*)(bias + nc);
            if (m < N) {
                ushort4 o;
                o.x = f2b(acc[0] + b4.x);
                o.y = f2b(acc[1] + b4.y);
                o.z = f2b(acc[2] + b4.z);
                o.w = f2b(acc[3] + b4.w);
                *(ushort4*)(Hb + (size_t)m * 256 + nc) = o;
            }
        }
    }
}

// ================================================================ column stats bf16 [N][256] — vectorized uint4 loads
__global__ __launch_bounds__(256) void stats_hid_b(const short* __restrict__ H, int N,
                                                   float* __restrict__ sum, float* __restrict__ sumsq) {
    __shared__ float red[8 * 256];
    int tid = threadIdx.x;
    int c8 = tid & 31;
    int rg = tid >> 5;
    float s[8], q[8];
    #pragma unroll
    for (int j = 0; j < 8; ++j) { s[j] = 0.f; q[j] = 0.f; }
    for (int r = blockIdx.x * 8 + rg; r < N; r += gridDim.x * 8) {
        uint4 v = *(const uint4*)(H + (size_t)r * 256 + c8 * 8);
        #pragma unroll
        for (int j = 0; j < 8; ++j) {
            float f = b2f(((const unsigned short*)&v)[j]);
            s[j] += f; q[j] += f * f;
        }
    }
    #pragma unroll
    for (int j = 0; j < 8; ++j) red[rg * 256 + c8 * 8 + j] = s[j];
    __syncthreads();
    {
        float t = 0.f;
        #pragma unroll
        for (int g = 0; g < 8; ++g) t += red[g * 256 + tid];
        atomicAdd(&sum[tid], t);
    }
    __syncthreads();
    #pragma unroll
    for (int j = 0; j < 8; ++j) red[rg * 256 + c8 * 8 + j] = q[j];
    __syncthreads();
    {
        float t = 0.f;
        #pragma unroll
        for (int g = 0; g < 8; ++g) t += red[g * 256 + tid];
        atomicAdd(&sumsq[tid], t);
    }
}

// ================================================================ GEMM2 (MFMA, BM=64): z = relu(bn1(hpreb)) @ W2 -> bf16 [N][40]
__global__ __launch_bounds__(256) void gemm2_mfma(const short* __restrict__ Hb,
                                                  const short* __restrict__ Wtb,
                                                  const float* __restrict__ colsum, const float* __restrict__ colsumsq,
                                                  const float* __restrict__ gamma, const float* __restrict__ beta,
                                                  float invN, short* __restrict__ Zb, int N) {
    __shared__ short Al[64 * 136];
    __shared__ short Wl[48 * 136];
    __shared__ float scl[D_HID], shl[D_HID];
    int tid = threadIdx.x;
    {
        float m = colsum[tid] * invN;
        float var = colsumsq[tid] * invN - m * m;
        float rstd = rsqrtf(var + BN_EPS);
        float sc = rstd * gamma[tid];
        scl[tid] = sc;
        shl[tid] = beta[tid] - m * sc;
    }
    int r0 = blockIdx.x * 64;
    int w = tid >> 6, l = tid & 63;
    int r16 = l & 15, g4 = l >> 4;
    int chunk = tid & 15, rbase = tid >> 4;
    f32x4 acc[3];
    #pragma unroll
    for (int n = 0; n < 3; ++n)
        acc[n] = (f32x4){0.f, 0.f, 0.f, 0.f};

    #pragma unroll
    for (int h = 0; h < 2; ++h) {
        __syncthreads();                 // h=0: scl ready; h=1: prev compute done
        int kb = h * 128;
        #pragma unroll
        for (int p = 0; p < 4; ++p) {    // stage A half [64][16ch] with BN+ReLU
            int row = p * 16 + rbase;
            int m = r0 + row;
            uint4 v = make_uint4(0, 0, 0, 0);
            if (m < N) v = *(const uint4*)(Hb + (size_t)m * 256 + kb + chunk * 8);
            unsigned short* us = (unsigned short*)&v;
            #pragma unroll
            for (int j = 0; j < 8; ++j) {
                int k = kb + chunk * 8 + j;
                float f = b2f(us[j]);
                f = fmaxf(f * scl[k] + shl[k], 0.f);
                us[j] = f2b(f);
            }
            *(uint4*)(Al + row * 136 + chunk * 8) = v;
        }
        #pragma unroll
        for (int p = 0; p < 3; ++p) {    // stage Wt2 half [48][16ch]
            int row = p * 16 + rbase;
            *(uint4*)(Wl + row * 136 + chunk * 8) =
                *(const uint4*)(Wtb + (size_t)row * 256 + kb + chunk * 8);
        }
        __syncthreads();
        bf16x8 wf[3][4];
        #pragma unroll
        for (int n = 0; n < 3; ++n)
            #pragma unroll
            for (int k = 0; k < 4; ++k)
                wf[n][k] = *(bf16x8*)(Wl + (n * 16 + r16) * 136 + k * 32 + g4 * 8);
        #pragma unroll
        for (int k = 0; k < 4; ++k) {
            bf16x8 af = *(bf16x8*)(Al + (w * 16 + r16) * 136 + k * 32 + g4 * 8);
            #pragma unroll
            for (int n = 0; n < 3; ++n)
                acc[n] = __builtin_amdgcn_mfma_f32_16x16x32_bf16(wf[n][k], af, acc[n], 0, 0, 0);
        }
    }
    int m = r0 + w * 16 + r16;
    if (m < N) {
        #pragma unroll
        for (int n = 0; n < 3; ++n) {
            int nc = n * 16 + g4 * 4;
            if (nc < D_OUT) {
                ushort4 o;
                o.x = f2b(acc[n][0]);
                o.y = f2b(acc[n][1]);
                o.z = f2b(acc[n][2]);
                o.w = f2b(acc[n][3]);
                *(ushort4*)(Zb + (size_t)m * D_OUT + nc) = o;
            }
        }
    }
}

// ================================================================ gather2 + fused column stats (bf16 z, bf16 h2 out, 8/4/1 ILP)
__global__ __launch_bounds__(256) void gather2_stats(const short* __restrict__ Zb,
        const int* __restrict__ rp, const int* __restrict__ csr,
        const float* __restrict__ bias, short* __restrict__ H2b,
        float* __restrict__ gsum, float* __restrict__ gsumsq, int N) {
    __shared__ float ls[D_OUT], lq[D_OUT];
    int tid = threadIdx.x;
    if (tid < D_OUT) { ls[tid] = 0.f; lq[tid] = 0.f; }
    __syncthreads();
    int t = blockIdx.x * 256 + tid;
    int n = t / 5, c = t - n * 5;
    if (n < N) {
        const uint4* Zc = (const uint4*)Zb + c;
        float acc[8];
        {
            uint4 v = Zc[(size_t)n * 5];
            #pragma unroll
            for (int j = 0; j < 8; ++j) acc[j] = b2f(((const unsigned short*)&v)[j]);
        }
        int e0 = rp[n], e1 = rp[n + 1];
        int e = e0;
        for (; e + 8 <= e1; e += 8) {
            int si[8];
            #pragma unroll
            for (int q = 0; q < 8; ++q) si[q] = csr[e + q];
            uint4 u[8];
            #pragma unroll
            for (int q = 0; q < 8; ++q) u[q] = Zc[(size_t)si[q] * 5];
            #pragma unroll
            for (int j = 0; j < 8; ++j) {
                float a0 = 0.f, a1 = 0.f;
                #pragma unroll
                for (int q = 0; q < 8; q += 2) {
                    a0 += b2f(((const unsigned short*)&u[q])[j]);
                    a1 += b2f(((const unsigned short*)&u[q + 1])[j]);
                }
                acc[j] += a0 + a1;
            }
        }
        for (; e + 4 <= e1; e += 4) {
            int s0 = csr[e], s1 = csr[e + 1], s2 = csr[e + 2], s3 = csr[e + 3];
            uint4 u0 = Zc[(size_t)s0 * 5];
            uint4 u1 = Zc[(size_t)s1 * 5];
            uint4 u2 = Zc[(size_t)s2 * 5];
            uint4 u3 = Zc[(size_t)s3 * 5];
            #pragma unroll
            for (int j = 0; j < 8; ++j)
                acc[j] += (b2f(((const unsigned short*)&u0)[j]) + b2f(((const unsigned short*)&u1)[j]))
                        + (b2f(((const unsigned short*)&u2)[j]) + b2f(((const unsigned short*)&u3)[j]));
        }
        for (; e < e1; ++e) {
            int s = csr[e];
            uint4 u = Zc[(size_t)s * 5];
            #pragma unroll
            for (int j = 0; j < 8; ++j) acc[j] += b2f(((const unsigned short*)&u)[j]);
        }
        int cc = c * 8;
        unsigned short o[8];
        #pragma unroll
        for (int j = 0; j < 8; ++j) {
            acc[j] += bias[cc + j];
            atomicAdd(&ls[cc + j], acc[j]);
            atomicAdd(&lq[cc + j], acc[j] * acc[j]);
            o[j] = f2b(acc[j]);
        }
        *(uint4*)(H2b + (size_t)n * D_OUT + cc) = *(uint4*)o;
    }
    __syncthreads();
    if (tid < D_OUT) {
        atomicAdd(&gsum[tid], ls[tid]);
        atomicAdd(&gsumsq[tid], lq[tid]);
    }
}

// ================================================================ BN2 + log_softmax (bf16 input)
__global__ __launch_bounds__(256) void bn_logsoftmax(const short* __restrict__ Hb,
                                                     const float* __restrict__ colsum, const float* __restrict__ colsumsq,
                                                     const float* __restrict__ gamma, const float* __restrict__ beta,
                                                     float invN, float* __restrict__ out, int N) {
    __shared__ float buf[256 * 41];
    __shared__ float scl[D_OUT], shl[D_OUT];
    int tid = threadIdx.x;
    if (tid < D_OUT) {
        float m = colsum[tid] * invN;
        float var = colsumsq[tid] * invN - m * m;
        float rstd = rsqrtf(var + BN_EPS);
        float sc = rstd * gamma[tid];
        scl[tid] = sc;
        shl[tid] = beta[tid] - m * sc;
    }
    const unsigned short* Hu = (const unsigned short*)Hb;
    int r0 = blockIdx.x * 256;
    int nrow = min(256, N - r0);
    int total = nrow * D_OUT;
    __syncthreads();
    for (int i = tid; i < total; i += 256)
        buf[i + i / D_OUT] = b2f(Hu[(size_t)r0 * D_OUT + i]);
    __syncthreads();
    if (tid < nrow) {
        int base = tid * 41;
        float m = -1e30f;
        #pragma unroll
        for (int j = 0; j < D_OUT; ++j) {
            float v = buf[base + j] * scl[j] + shl[j];
            buf[base + j] = v;
            m = fmaxf(m, v);
        }
        float s = 0.f;
        #pragma unroll
        for (int j = 0; j < D_OUT; ++j)
            s += expf(buf[base + j] - m);
        float lse = m + logf(s);
        #pragma unroll
        for (int j = 0; j < D_OUT; ++j)
            buf[base + j] -= lse;
    }
    __syncthreads();
    for (int i = tid; i < total; i += 256)
        out[(size_t)r0 * D_OUT + i] = buf[i + i / D_OUT];
}

// =================================================================
extern "C" void kernel_launch(void* const* d_in, const int* in_sizes, int n_in,
                              void* d_out, int out_size, void* d_ws, size_t ws_size,
                              hipStream_t stream) {
    const float* x      = (const float*)d_in[0];
    const int*   ei     = (const int*)d_in[1];
    const float* W1     = (const float*)d_in[2];
    const float* b1     = (const float*)d_in[3];
    const float* W2     = (const float*)d_in[4];
    const float* b2     = (const float*)d_in[5];
    const float* gamma1 = (const float*)d_in[6];
    const float* beta1  = (const float*)d_in[7];
    const float* gamma2 = (const float*)d_in[8];
    const float* beta2  = (const float*)d_in[9];
    float* out = (float*)d_out;

    const int N = in_sizes[0] / D_IN;      // 50000
    const int E = in_sizes[1] / 2;         // 800000
    const int* src = ei;
    const int* dst = ei + E;
    const int nbk = (N + 255) >> BSHIFT;   // 196
    const int nconv = (N * XC + 255) / 256;

    // ---------------- workspace layout ----------------
    short* xb    = (short*)d_ws;                       // N*104 bf16
    short* hpreb = xb + (size_t)N * (XC * 8);          // N*256 bf16
    short* Wt1b  = hpreb + (size_t)N * 256;            // 256*128
    short* Wt2b  = Wt1b + 256 * 128;                   // 48*256
    short* zb    = Wt2b + 48 * 256;                    // N*40 bf16
    short* h2b   = zb + (size_t)N * D_OUT;             // N*40 bf16
    float* stats = (float*)(h2b + (size_t)N * D_OUT + 64);  // 640 f32
    float* colsum1   = stats + 0;     // 256
    float* colsumsq1 = stats + 256;   // 256
    float* colsum2   = stats + 512;   // 40 (pad 64)
    float* colsumsq2 = stats + 576;   // 40 (pad 64)
    int* rp       = (int*)(stats + 640);  // N+1 (pad N+4)
    int* hpartial = rp + N + 4;           // 64*256
    int* bbase    = hpartial + NHIST*256; // 260
    int* bcursor  = bbase + 260;          // 256
    int* csr      = bcursor + 256;        // E
    unsigned* pairs = (unsigned*)(csr + E);  // E (packed)

    // ---------------- fused prep + CSR build ----------------
    preprocess<<<nconv + NHIST + 23, 256, 0, stream>>>(x, xb, N, nconv, dst, E, hpartial,
                                                       W1, W2, Wt1b, Wt2b, stats);
    bucket_scan<<<1, 256, 0, stream>>>(hpartial, bbase, bcursor, rp, nbk, N, E);
    partition_edges<<<(E + P2_EPB - 1) / P2_EPB, 256, 0, stream>>>(src, dst, bcursor, pairs, E);
    build_csr<<<nbk, 256, 0, stream>>>(pairs, bbase, rp, csr, N);

    // ---------------- layer 1 (gather fused into GEMM1, BM=64, staged Wl) ----------------
    gemm1_fused<<<(N + 63) / 64, 256, 0, stream>>>(xb, rp, csr, Wt1b, b1, hpreb, N);
    stats_hid_b<<<512, 256, 0, stream>>>(hpreb, N, colsum1, colsumsq1);

    // ---------------- layer 2 (BM=64) ----------------
    gemm2_mfma<<<(N + 63) / 64, 256, 0, stream>>>(hpreb, Wt2b, colsum1, colsumsq1,
                                                  gamma1, beta1, 1.0f / N, zb, N);
    gather2_stats<<<(N * 5 + 255) / 256, 256, 0, stream>>>(zb, rp, csr, b2, h2b,
                                                           colsum2, colsumsq2, N);

    // ---------------- BN2 + log_softmax ----------------
    bn_logsoftmax<<<(N + 255) / 256, 256, 0, stream>>>(h2b, colsum2, colsumsq2,
                                                       gamma2, beta2, 1.0f / N, out, N);
}